// Round 1
// baseline (1516.175 us; speedup 1.0000x reference)
//
#include <hip/hip_runtime.h>
#include <math.h>

#define C_DIM 256
#define NH 8
#define HD 32
#define Q_DIM 1000
#define N_PTS 16
#define B_DIM 16
#define H_IMG 100
#define W_IMG 100
#define HW 10000
#define BQ2 2
#define NS 32   // samples per block = BQ2*16

// ---------------------------------------------------------------------------
// K0: transpose x [B,C,H*W] -> xt [B,H*W,C]  (NHWC for coalesced gathers)
// ---------------------------------------------------------------------------
__global__ __launch_bounds__(256) void transpose_kernel(
    const float* __restrict__ x, float* __restrict__ xt) {
  __shared__ float t[32][33];
  int b  = blockIdx.z;
  int c0 = blockIdx.y * 32;
  int p0 = blockIdx.x * 32;
  int tx = threadIdx.x, ty = threadIdx.y;
#pragma unroll
  for (int k = 0; k < 4; ++k) {
    int ci = ty + 8 * k;
    int p = p0 + tx;
    if (p < HW) t[ci][tx] = x[((size_t)b * C_DIM + (c0 + ci)) * HW + p];
  }
  __syncthreads();
#pragma unroll
  for (int k = 0; k < 4; ++k) {
    int j = ty + 8 * k;
    int p = p0 + j;
    if (p < HW) xt[((size_t)b * HW + p) * C_DIM + (c0 + tx)] = t[tx][j];
  }
}

// ---------------------------------------------------------------------------
// K1: qp = q @ wq^T + bq   [16000,256]
// block computes 16 rows x 256 cols; thread owns one output column.
// ---------------------------------------------------------------------------
__global__ __launch_bounds__(256) void qp_kernel(
    const float* __restrict__ q, const float* __restrict__ wq,
    const float* __restrict__ bq, float* __restrict__ qp) {
  __shared__ float qrows[16][257];
  int row0 = blockIdx.x * 16;
  int tid = threadIdx.x;
  for (int t = tid; t < 16 * C_DIM; t += 256) {
    int r = t >> 8, c = t & 255;
    qrows[r][c] = q[(size_t)(row0 + r) * C_DIM + c];
  }
  __syncthreads();
  float acc[16];
  float b0 = bq[tid];
#pragma unroll
  for (int r = 0; r < 16; ++r) acc[r] = b0;
  const float* wrow = wq + (size_t)tid * C_DIM;
  for (int cc = 0; cc < C_DIM; ++cc) {
    float w = wrow[cc];
#pragma unroll
    for (int r = 0; r < 16; ++r) acc[r] += qrows[r][cc] * w;
  }
#pragma unroll
  for (int r = 0; r < 16; ++r) qp[(size_t)(row0 + r) * C_DIM + tid] = acc[r];
}

// ---------------------------------------------------------------------------
// K2: fused gather + qk-fold + softmax + pv + output projection.
// One block handles (b, 2 queries) = 32 samples. 256 threads.
// ---------------------------------------------------------------------------
__global__ __launch_bounds__(256) void attn_kernel(
    const float* __restrict__ src, int strB, int strY, int strX, int strC,
    const float* __restrict__ ref,
    const float* __restrict__ qp,   // may be null -> inline fallback
    const float* __restrict__ q, const float* __restrict__ wq,
    const float* __restrict__ bq,
    const float* __restrict__ wk, const float* __restrict__ bk,
    const float* __restrict__ wv, const float* __restrict__ bv,
    float* __restrict__ out) {
  __shared__ float qp_s[BQ2][C_DIM];   // later aliased as logit storage
  __shared__ float qkpv[16][257];      // qk then (after barrier) pv
  __shared__ float samp[NS][257];
  __shared__ float p_s[16][16];
  __shared__ float qbk_s[16];
  float* logit_s = &qp_s[0][0];        // qp_s dead after P1

  int tid = threadIdx.x;
  int q2g = blockIdx.x;                // 0..499
  int b = blockIdx.y;
  int q2_0 = q2g * BQ2;
  int m0 = q2g * NS;

  // ---- P0: load (or compute) the two qp rows ----
  if (qp) {
#pragma unroll
    for (int r = 0; r < BQ2; ++r)
      qp_s[r][tid] = qp[((size_t)b * Q_DIM + q2_0 + r) * C_DIM + tid];
  } else {
#pragma unroll
    for (int r = 0; r < BQ2; ++r) {
      float acc = bq[tid];
      const float* qrow = q + ((size_t)b * Q_DIM + q2_0 + r) * C_DIM;
      const float* wrow = wq + (size_t)tid * C_DIM;
      for (int cc = 0; cc < C_DIM; ++cc) acc += qrow[cc] * wrow[cc];
      qp_s[r][tid] = acc;
    }
  }
  __syncthreads();

  // ---- P1: qk[pair][c'] = sum_dd qp[q2l][h*32+dd] * wk[h*32+dd][c'] ----
  // pair = q2l*8 + h. One pass over wk (coalesced), both queries share it.
#pragma unroll 1
  for (int h = 0; h < NH; ++h) {
    float a0 = 0.f, a1 = 0.f;
#pragma unroll
    for (int dd = 0; dd < HD; ++dd) {
      float w = wk[(size_t)(h * HD + dd) * C_DIM + tid];
      a0 += qp_s[0][h * HD + dd] * w;
      a1 += qp_s[1][h * HD + dd] * w;
    }
    qkpv[h][tid] = a0;
    qkpv[8 + h][tid] = a1;
  }
  if (tid < 16) {
    int q2l = tid >> 3, h = tid & 7;
    float a = 0.f;
#pragma unroll
    for (int dd = 0; dd < HD; ++dd) a += qp_s[q2l][h * HD + dd] * bk[h * HD + dd];
    qbk_s[tid] = a;
  }

  // ---- P2: bilinear gather of 32 samples, thread = channel ----
  {
    int coff = tid * strC;
#pragma unroll 1
    for (int i = 0; i < NS; ++i) {
      int m = m0 + i;
      int qq = m % Q_DIM;
      int nn = m / Q_DIM;
      const float* rp = ref + (((size_t)b * Q_DIM + qq) * N_PTS + nn) * 2;
      float gx = (rp[0] + 1.f) * (0.5f * W_IMG) - 0.5f;
      float gy = (rp[1] + 1.f) * (0.5f * H_IMG) - 0.5f;
      float fx0 = floorf(gx), fy0 = floorf(gy);
      float fx = gx - fx0, fy = gy - fy0;
      int ix0 = (int)fx0, iy0 = (int)fy0;
      int ix1 = ix0 + 1, iy1 = iy0 + 1;
      float w00 = (1.f - fx) * (1.f - fy);
      float w01 = fx * (1.f - fy);
      float w10 = (1.f - fx) * fy;
      float w11 = fx * fy;
      size_t base = (size_t)(b * strB + coff);
      float v = 0.f;
      if (ix0 >= 0 && ix0 < W_IMG) {
        if (iy0 >= 0 && iy0 < H_IMG) v += w00 * src[base + (size_t)iy0 * strY + (size_t)ix0 * strX];
        if (iy1 >= 0 && iy1 < H_IMG) v += w10 * src[base + (size_t)iy1 * strY + (size_t)ix0 * strX];
      }
      if (ix1 >= 0 && ix1 < W_IMG) {
        if (iy0 >= 0 && iy0 < H_IMG) v += w01 * src[base + (size_t)iy0 * strY + (size_t)ix1 * strX];
        if (iy1 >= 0 && iy1 < H_IMG) v += w11 * src[base + (size_t)iy1 * strY + (size_t)ix1 * strX];
      }
      samp[i][tid] = v;
    }
  }
  __syncthreads();

  // ---- P3: logits. thread -> (pair, n2); one 256-dot each ----
  {
    int pair = tid >> 4;          // q2l*8 + h
    int n2 = tid & 15;
    int q2l = pair >> 3;
    int i = q2l * 16 + n2;
    float acc = 0.f;
    for (int cc = 0; cc < C_DIM; ++cc)
      acc += qkpv[pair][cc] * samp[i][cc];
    float lg = (acc + qbk_s[pair]) * 0.17677669529663687f;  // 1/sqrt(32)
    __syncthreads();              // all qp_s/qkpv reads done before alias write
    logit_s[tid] = lg;
  }
  __syncthreads();

  // ---- softmax over n2 per (pair) ----
  if (tid < 16) {
    float mx = -1e30f;
#pragma unroll
    for (int n2 = 0; n2 < 16; ++n2) mx = fmaxf(mx, logit_s[tid * 16 + n2]);
    float s = 0.f;
    float e[16];
#pragma unroll
    for (int n2 = 0; n2 < 16; ++n2) {
      e[n2] = __expf(logit_s[tid * 16 + n2] - mx);
      s += e[n2];
    }
    float inv = 1.f / s;
#pragma unroll
    for (int n2 = 0; n2 < 16; ++n2) p_s[tid][n2] = e[n2] * inv;
  }
  __syncthreads();

  // ---- P4: pv[pair][c'] = sum_n2 p * samp  (overwrites qk) ----
#pragma unroll 1
  for (int pair = 0; pair < 16; ++pair) {
    int q2l = pair >> 3;
    float acc = 0.f;
#pragma unroll
    for (int n2 = 0; n2 < 16; ++n2)
      acc += p_s[pair][n2] * samp[q2l * 16 + n2][tid];
    qkpv[pair][tid] = acc;
  }
  __syncthreads();

  // ---- P5: out[c_out] = sum_c' pv[h(c_out)][c'] * wv[c_out][c'] + bv ----
  {
    int h = tid >> 5;
#pragma unroll
    for (int q2l = 0; q2l < BQ2; ++q2l) {
      float acc = bv[tid];
      const float* wrow = wv + (size_t)tid * C_DIM;
      const float* pvrow = &qkpv[q2l * 8 + h][0];
      for (int cc = 0; cc < C_DIM; ++cc)
        acc += pvrow[cc] * wrow[cc];
      out[((size_t)b * Q_DIM + q2_0 + q2l) * C_DIM + tid] = acc;
    }
  }
}

// ---------------------------------------------------------------------------
extern "C" void kernel_launch(void* const* d_in, const int* in_sizes, int n_in,
                              void* d_out, int out_size, void* d_ws, size_t ws_size,
                              hipStream_t stream) {
  const float* x   = (const float*)d_in[0];
  const float* q   = (const float*)d_in[1];
  const float* ref = (const float*)d_in[2];
  const float* wq  = (const float*)d_in[3];
  const float* bq  = (const float*)d_in[4];
  const float* wk  = (const float*)d_in[5];
  const float* bk  = (const float*)d_in[6];
  const float* wv  = (const float*)d_in[7];
  const float* bv  = (const float*)d_in[8];
  float* out = (float*)d_out;

  const size_t QP_BYTES = (size_t)B_DIM * Q_DIM * C_DIM * 4;  // 16.384 MB
  const size_t XT_BYTES = (size_t)B_DIM * HW * C_DIM * 4;     // 163.84 MB
  float* qp = nullptr;
  float* xt = nullptr;
  if (ws_size >= QP_BYTES) qp = (float*)d_ws;
  if (ws_size >= QP_BYTES + XT_BYTES) xt = (float*)((char*)d_ws + QP_BYTES);

  if (xt) {
    dim3 g((HW + 31) / 32, C_DIM / 32, B_DIM);
    transpose_kernel<<<g, dim3(32, 8), 0, stream>>>(x, xt);
  }
  if (qp) {
    qp_kernel<<<B_DIM * Q_DIM / 16, 256, 0, stream>>>(q, wq, bq, qp);
  }

  const float* src;
  int sB, sY, sX, sC;
  if (xt) { src = xt; sB = HW * C_DIM; sY = W_IMG * C_DIM; sX = C_DIM; sC = 1; }
  else    { src = x;  sB = C_DIM * HW; sY = W_IMG;         sX = 1;     sC = HW; }

  attn_kernel<<<dim3(Q_DIM / BQ2, B_DIM), 256, 0, stream>>>(
      src, sB, sY, sX, sC, ref, qp, q, wq, bq, wk, bk, wv, bv, out);
}

// Round 2
// 761.749 us; speedup vs baseline: 1.9904x; 1.9904x over previous
//
#include <hip/hip_runtime.h>
#include <math.h>

typedef float f4 __attribute__((ext_vector_type(4)));

#define C_DIM 256
#define NH 8
#define HD 32
#define Q_DIM 1000
#define N_PTS 16
#define B_DIM 16
#define H_IMG 100
#define W_IMG 100
#define HW 10000
#define BQ2 2
#define NS 32   // samples per block = BQ2*16

// ---------------------------------------------------------------------------
// Generic 32x32-tile transpose: in [batch][rows][cols] -> out [batch][cols][rows]
// ---------------------------------------------------------------------------
__global__ __launch_bounds__(256) void transpose_kernel(
    const float* __restrict__ in, float* __restrict__ out, int rows, int cols) {
  __shared__ float t[32][33];
  size_t off = (size_t)blockIdx.z * rows * cols;
  int r0 = blockIdx.y * 32, c0 = blockIdx.x * 32;
  int tx = threadIdx.x, ty = threadIdx.y;
#pragma unroll
  for (int k = 0; k < 4; ++k) {
    int r = r0 + ty + 8 * k, c = c0 + tx;
    if (r < rows && c < cols) t[ty + 8 * k][tx] = in[off + (size_t)r * cols + c];
  }
  __syncthreads();
#pragma unroll
  for (int k = 0; k < 4; ++k) {
    int c = c0 + ty + 8 * k, r = r0 + tx;
    if (r < rows && c < cols) out[off + (size_t)c * rows + r] = t[tx][ty + 8 * k];
  }
}

// ---------------------------------------------------------------------------
// qp = q @ wq^T + bq  using pre-transposed wqT [cin][cout]. 32 rows per block.
// thread = (rg in 4, co4 in 64); acc = 8 rows x float4.
// ---------------------------------------------------------------------------
__global__ __launch_bounds__(256) void qp_fast_kernel(
    const float* __restrict__ q, const float* __restrict__ wqT,
    const float* __restrict__ bq, float* __restrict__ qp) {
  __shared__ __align__(16) float q_s[32][260];
  int tid = threadIdx.x;
  int r0 = blockIdx.x * 32;
#pragma unroll 1
  for (int k = 0; k < 8; ++k) {
    int task = k * 256 + tid;
    int r = task >> 6, c4 = task & 63;
    *(f4*)&q_s[r][c4 * 4] =
        *(const f4*)(q + (size_t)(r0 + r) * C_DIM + c4 * 4);
  }
  __syncthreads();
  int rg = tid >> 6, co4 = tid & 63;
  f4 acc[8];
#pragma unroll
  for (int r = 0; r < 8; ++r) acc[r] = {0.f, 0.f, 0.f, 0.f};
#pragma unroll 2
  for (int cc4 = 0; cc4 < 64; ++cc4) {
    f4 w0 = *(const f4*)(wqT + (size_t)(cc4 * 4 + 0) * C_DIM + co4 * 4);
    f4 w1 = *(const f4*)(wqT + (size_t)(cc4 * 4 + 1) * C_DIM + co4 * 4);
    f4 w2 = *(const f4*)(wqT + (size_t)(cc4 * 4 + 2) * C_DIM + co4 * 4);
    f4 w3 = *(const f4*)(wqT + (size_t)(cc4 * 4 + 3) * C_DIM + co4 * 4);
#pragma unroll
    for (int r = 0; r < 8; ++r) {
      f4 qv = *(const f4*)&q_s[rg * 8 + r][cc4 * 4];
      acc[r] += qv[0] * w0 + qv[1] * w1 + qv[2] * w2 + qv[3] * w3;
    }
  }
  f4 bq4 = *(const f4*)(bq + co4 * 4);
#pragma unroll
  for (int r = 0; r < 8; ++r) {
    f4 v = acc[r] + bq4;
    *(f4*)(qp + (size_t)(r0 + rg * 8 + r) * C_DIM + co4 * 4) = v;
  }
}

// ---------------------------------------------------------------------------
// Old qp kernel (fallback when no wqT workspace)
// ---------------------------------------------------------------------------
__global__ __launch_bounds__(256) void qp_kernel(
    const float* __restrict__ q, const float* __restrict__ wq,
    const float* __restrict__ bq, float* __restrict__ qp) {
  __shared__ float qrows[16][257];
  int row0 = blockIdx.x * 16;
  int tid = threadIdx.x;
  for (int t = tid; t < 16 * C_DIM; t += 256) {
    int r = t >> 8, c = t & 255;
    qrows[r][c] = q[(size_t)(row0 + r) * C_DIM + c];
  }
  __syncthreads();
  float acc[16];
  float b0 = bq[tid];
#pragma unroll
  for (int r = 0; r < 16; ++r) acc[r] = b0;
  const float* wrow = wq + (size_t)tid * C_DIM;
  for (int cc = 0; cc < C_DIM; ++cc) {
    float w = wrow[cc];
#pragma unroll
    for (int r = 0; r < 16; ++r) acc[r] += qrows[r][cc] * w;
  }
#pragma unroll
  for (int r = 0; r < 16; ++r) qp[(size_t)(row0 + r) * C_DIM + tid] = acc[r];
}

// ---------------------------------------------------------------------------
// K2: fused gather + qk-fold + softmax + pv + output projection (float4).
// One block = (b, 2 queries) = 32 samples. 256 threads.
// ---------------------------------------------------------------------------
__global__ __launch_bounds__(256) void attn_kernel(
    const float* __restrict__ src, int strB, int strY, int strX, int strC,
    const float* __restrict__ ref,
    const float* __restrict__ qp,   // may be null -> inline fallback
    const float* __restrict__ q, const float* __restrict__ wq,
    const float* __restrict__ bq,
    const float* __restrict__ wk, const float* __restrict__ bk,
    const float* __restrict__ wvt,  // wv^T [cin][cout], may be null
    const float* __restrict__ wv, const float* __restrict__ bv,
    float* __restrict__ out) {
  __shared__ __align__(16) float qp_s[BQ2][C_DIM];
  __shared__ __align__(16) float qk_s[16][260];   // qk, then pv after P4
  __shared__ __align__(16) float samp[NS][260];
  __shared__ float p_s[16][16];
  __shared__ float qbk_s[16];
  __shared__ float logit_s[256];

  int tid = threadIdx.x;
  int q2g = blockIdx.x;                // 0..499
  int b = blockIdx.y;
  int q2_0 = q2g * BQ2;
  int m0 = q2g * NS;
  int c4 = tid & 63;
  int grp = tid >> 6;                  // wave id 0..3

  // ---- P0: load (or compute) the two qp rows ----
  if (qp) {
    if (tid < 128) {
      int r = tid >> 6, cc4 = tid & 63;
      *(f4*)&qp_s[r][cc4 * 4] =
          *(const f4*)(qp + ((size_t)b * Q_DIM + q2_0 + r) * C_DIM + cc4 * 4);
    }
  } else {
#pragma unroll
    for (int r = 0; r < BQ2; ++r) {
      float acc = bq[tid];
      const float* qrow = q + ((size_t)b * Q_DIM + q2_0 + r) * C_DIM;
      const float* wrow = wq + (size_t)tid * C_DIM;
      for (int cc = 0; cc < C_DIM; ++cc) acc += qrow[cc] * wrow[cc];
      qp_s[r][tid] = acc;
    }
  }

  // ---- P2: bilinear gather of 32 samples ----
  if (strC == 1) {
    // fast path: NHWC src, wave = one sample, lanes = 64 float4 channel groups
    const float* base = src + (size_t)b * HW * C_DIM + c4 * 4;
#pragma unroll 1
    for (int k = 0; k < 8; ++k) {
      int i = k * 4 + grp;
      int m = m0 + i;
      int qq = m % Q_DIM;
      int nn = m / Q_DIM;
      const float* rp = ref + (((size_t)b * Q_DIM + qq) * N_PTS + nn) * 2;
      float gx = (rp[0] + 1.f) * 50.f - 0.5f;
      float gy = (rp[1] + 1.f) * 50.f - 0.5f;
      float fx0 = floorf(gx), fy0 = floorf(gy);
      float fx = gx - fx0, fy = gy - fy0;
      int ix0 = (int)fx0, iy0 = (int)fy0;
      int ix1 = ix0 + 1, iy1 = iy0 + 1;
      bool x0ok = (ix0 >= 0) & (ix0 < W_IMG);
      bool x1ok = (ix1 >= 0) & (ix1 < W_IMG);
      bool y0ok = (iy0 >= 0) & (iy0 < H_IMG);
      bool y1ok = (iy1 >= 0) & (iy1 < H_IMG);
      f4 acc = {0.f, 0.f, 0.f, 0.f};
      if (x0ok && y0ok)
        acc += ((1.f - fx) * (1.f - fy)) *
               *(const f4*)(base + (size_t)(iy0 * W_IMG + ix0) * C_DIM);
      if (x1ok && y0ok)
        acc += (fx * (1.f - fy)) *
               *(const f4*)(base + (size_t)(iy0 * W_IMG + ix1) * C_DIM);
      if (x0ok && y1ok)
        acc += ((1.f - fx) * fy) *
               *(const f4*)(base + (size_t)(iy1 * W_IMG + ix0) * C_DIM);
      if (x1ok && y1ok)
        acc += (fx * fy) *
               *(const f4*)(base + (size_t)(iy1 * W_IMG + ix1) * C_DIM);
      *(f4*)&samp[i][c4 * 4] = acc;
    }
  } else {
    // fallback: strided (NCHW) scalar gather, thread = channel
    int coff = tid * strC;
#pragma unroll 1
    for (int i = 0; i < NS; ++i) {
      int m = m0 + i;
      int qq = m % Q_DIM;
      int nn = m / Q_DIM;
      const float* rp = ref + (((size_t)b * Q_DIM + qq) * N_PTS + nn) * 2;
      float gx = (rp[0] + 1.f) * 50.f - 0.5f;
      float gy = (rp[1] + 1.f) * 50.f - 0.5f;
      float fx0 = floorf(gx), fy0 = floorf(gy);
      float fx = gx - fx0, fy = gy - fy0;
      int ix0 = (int)fx0, iy0 = (int)fy0;
      int ix1 = ix0 + 1, iy1 = iy0 + 1;
      float w00 = (1.f - fx) * (1.f - fy);
      float w01 = fx * (1.f - fy);
      float w10 = (1.f - fx) * fy;
      float w11 = fx * fy;
      size_t bse = (size_t)(b * strB + coff);
      float v = 0.f;
      if (ix0 >= 0 && ix0 < W_IMG) {
        if (iy0 >= 0 && iy0 < H_IMG) v += w00 * src[bse + (size_t)iy0 * strY + (size_t)ix0 * strX];
        if (iy1 >= 0 && iy1 < H_IMG) v += w10 * src[bse + (size_t)iy1 * strY + (size_t)ix0 * strX];
      }
      if (ix1 >= 0 && ix1 < W_IMG) {
        if (iy0 >= 0 && iy0 < H_IMG) v += w01 * src[bse + (size_t)iy0 * strY + (size_t)ix1 * strX];
        if (iy1 >= 0 && iy1 < H_IMG) v += w11 * src[bse + (size_t)iy1 * strY + (size_t)ix1 * strX];
      }
      samp[i][tid] = v;
    }
  }
  __syncthreads();

  // ---- P1: qk[pair][c'] = sum_dd qp[q2l][h*32+dd] * wk[h*32+dd][c'] ----
  // thread = (grp -> 2 heads, c4). pair = q2l*8 + h.
#pragma unroll 1
  for (int hh = 0; hh < 2; ++hh) {
    int h = grp * 2 + hh;
    f4 acc0 = {0.f, 0.f, 0.f, 0.f};
    f4 acc1 = {0.f, 0.f, 0.f, 0.f};
#pragma unroll 2
    for (int dd4 = 0; dd4 < 8; ++dd4) {
      f4 a0 = *(const f4*)&qp_s[0][h * HD + dd4 * 4];
      f4 a1 = *(const f4*)&qp_s[1][h * HD + dd4 * 4];
#pragma unroll
      for (int j = 0; j < 4; ++j) {
        f4 w4 = *(const f4*)(wk + (size_t)(h * HD + dd4 * 4 + j) * C_DIM + c4 * 4);
        acc0 += a0[j] * w4;
        acc1 += a1[j] * w4;
      }
    }
    *(f4*)&qk_s[h][c4 * 4] = acc0;
    *(f4*)&qk_s[8 + h][c4 * 4] = acc1;
  }
  if (tid < 16) {
    int q2l = tid >> 3, h = tid & 7;
    float a = 0.f;
#pragma unroll
    for (int dd4 = 0; dd4 < 8; ++dd4) {
      f4 qv = *(const f4*)&qp_s[q2l][h * HD + dd4 * 4];
      f4 b4 = *(const f4*)(bk + h * HD + dd4 * 4);
      a += qv[0] * b4[0] + qv[1] * b4[1] + qv[2] * b4[2] + qv[3] * b4[3];
    }
    qbk_s[tid] = a;
  }
  __syncthreads();

  // ---- P3: logits. thread = (pair, n2) ----
  {
    int pair = tid >> 4;
    int n2 = tid & 15;
    int i = (pair >> 3) * 16 + n2;
    float acc = 0.f;
#pragma unroll 4
    for (int cc4 = 0; cc4 < 64; ++cc4) {
      f4 qk4 = *(const f4*)&qk_s[pair][cc4 * 4];
      f4 s4 = *(const f4*)&samp[i][cc4 * 4];
      acc += qk4[0] * s4[0] + qk4[1] * s4[1] + qk4[2] * s4[2] + qk4[3] * s4[3];
    }
    logit_s[tid] = (acc + qbk_s[pair]) * 0.17677669529663687f;  // 1/sqrt(32)
  }
  __syncthreads();

  // ---- softmax over n2 per pair ----
  if (tid < 16) {
    float mx = -1e30f;
#pragma unroll
    for (int n2 = 0; n2 < 16; ++n2) mx = fmaxf(mx, logit_s[tid * 16 + n2]);
    float s = 0.f;
    float e[16];
#pragma unroll
    for (int n2 = 0; n2 < 16; ++n2) {
      e[n2] = __expf(logit_s[tid * 16 + n2] - mx);
      s += e[n2];
    }
    float inv = 1.f / s;
#pragma unroll
    for (int n2 = 0; n2 < 16; ++n2) p_s[tid][n2] = e[n2] * inv;
  }
  __syncthreads();

  // ---- P4: pv[pair][c'] = sum_n2 p * samp  (overwrites qk_s) ----
#pragma unroll 1
  for (int k = 0; k < 4; ++k) {
    int pair = k * 4 + grp;
    int roff = (pair >> 3) * 16;
    f4 acc = {0.f, 0.f, 0.f, 0.f};
#pragma unroll
    for (int n2 = 0; n2 < 16; ++n2)
      acc += p_s[pair][n2] * *(const f4*)&samp[roff + n2][c4 * 4];
    *(f4*)&qk_s[pair][c4 * 4] = acc;
  }
  __syncthreads();

  // ---- P5: out[c] = sum_cc pv[h(c)][cc] * wv[c][cc] + bv[c] ----
  {
    int h = tid >> 5;
    float acc0 = 0.f, acc1 = 0.f;
    if (wvt) {
#pragma unroll 4
      for (int cc4 = 0; cc4 < 64; ++cc4) {
        f4 pv0 = *(const f4*)&qk_s[h][cc4 * 4];
        f4 pv1 = *(const f4*)&qk_s[8 + h][cc4 * 4];
#pragma unroll
        for (int j = 0; j < 4; ++j) {
          float w = wvt[(size_t)(cc4 * 4 + j) * C_DIM + tid];
          acc0 += pv0[j] * w;
          acc1 += pv1[j] * w;
        }
      }
    } else {
#pragma unroll 4
      for (int cc4 = 0; cc4 < 64; ++cc4) {
        f4 pv0 = *(const f4*)&qk_s[h][cc4 * 4];
        f4 pv1 = *(const f4*)&qk_s[8 + h][cc4 * 4];
        f4 w4 = *(const f4*)(wv + (size_t)tid * C_DIM + cc4 * 4);
        acc0 += pv0[0] * w4[0] + pv0[1] * w4[1] + pv0[2] * w4[2] + pv0[3] * w4[3];
        acc1 += pv1[0] * w4[0] + pv1[1] * w4[1] + pv1[2] * w4[2] + pv1[3] * w4[3];
      }
    }
    float bvv = bv[tid];
    out[((size_t)b * Q_DIM + q2_0) * C_DIM + tid] = acc0 + bvv;
    out[((size_t)b * Q_DIM + q2_0 + 1) * C_DIM + tid] = acc1 + bvv;
  }
}

// ---------------------------------------------------------------------------
extern "C" void kernel_launch(void* const* d_in, const int* in_sizes, int n_in,
                              void* d_out, int out_size, void* d_ws, size_t ws_size,
                              hipStream_t stream) {
  const float* x   = (const float*)d_in[0];
  const float* q   = (const float*)d_in[1];
  const float* ref = (const float*)d_in[2];
  const float* wq  = (const float*)d_in[3];
  const float* bq  = (const float*)d_in[4];
  const float* wk  = (const float*)d_in[5];
  const float* bk  = (const float*)d_in[6];
  const float* wv  = (const float*)d_in[7];
  const float* bv  = (const float*)d_in[8];
  float* out = (float*)d_out;

  const size_t QP_BYTES = (size_t)B_DIM * Q_DIM * C_DIM * 4;  // 16.384 MB
  const size_t XT_BYTES = (size_t)B_DIM * HW * C_DIM * 4;     // 163.84 MB
  const size_t WT_BYTES = (size_t)C_DIM * C_DIM * 4;          // 256 KB

  float* qp  = nullptr;
  float* xt  = nullptr;
  float* wqT = nullptr;
  float* wvT = nullptr;
  if (ws_size >= QP_BYTES) qp = (float*)d_ws;
  if (ws_size >= QP_BYTES + XT_BYTES) xt = (float*)((char*)d_ws + QP_BYTES);
  if (ws_size >= QP_BYTES + XT_BYTES + 2 * WT_BYTES) {
    wqT = (float*)((char*)d_ws + QP_BYTES + XT_BYTES);
    wvT = (float*)((char*)d_ws + QP_BYTES + XT_BYTES + WT_BYTES);
  }

  if (xt) {
    dim3 g((HW + 31) / 32, C_DIM / 32, B_DIM);
    transpose_kernel<<<g, dim3(32, 8), 0, stream>>>(x, xt, C_DIM, HW);
  }
  if (wqT) {
    dim3 g(C_DIM / 32, C_DIM / 32, 1);
    transpose_kernel<<<g, dim3(32, 8), 0, stream>>>(wq, wqT, C_DIM, C_DIM);
    transpose_kernel<<<g, dim3(32, 8), 0, stream>>>(wv, wvT, C_DIM, C_DIM);
    qp_fast_kernel<<<B_DIM * Q_DIM / 32, 256, 0, stream>>>(q, wqT, bq, qp);
  } else if (qp) {
    qp_kernel<<<B_DIM * Q_DIM / 16, 256, 0, stream>>>(q, wq, bq, qp);
  }

  const float* src;
  int sB, sY, sX, sC;
  if (xt) { src = xt; sB = HW * C_DIM; sY = W_IMG * C_DIM; sX = C_DIM; sC = 1; }
  else    { src = x;  sB = C_DIM * HW; sY = W_IMG;         sX = 1;     sC = HW; }

  attn_kernel<<<dim3(Q_DIM / BQ2, B_DIM), 256, 0, stream>>>(
      src, sB, sY, sX, sC, ref, qp, q, wq, bq, wk, bk, wvT, wv, bv, out);
}

// Round 3
// 561.081 us; speedup vs baseline: 2.7022x; 1.3576x over previous
//
#include <hip/hip_runtime.h>
#include <math.h>

typedef float f4 __attribute__((ext_vector_type(4)));
typedef _Float16 half8 __attribute__((ext_vector_type(8)));

#define C_DIM 256
#define NH 8
#define HD 32
#define Q_DIM 1000
#define N_PTS 16
#define B_DIM 16
#define H_IMG 100
#define W_IMG 100
#define HW 10000
#define BQ2 2
#define NS 32

// ===========================================================================
// NEW PATH (f16 + MFMA)
// ===========================================================================

// ---- x [B,C,HW] f32 -> xt [B,HW,C] f16 ------------------------------------
__global__ __launch_bounds__(256) void xt_kernel(
    const float* __restrict__ x, _Float16* __restrict__ xt) {
  __shared__ float t[64][65];
  int p0 = blockIdx.x * 64;
  int c0 = blockIdx.y * 64;
  int b = blockIdx.z;
  int tid = threadIdx.x;
  int p4 = tid & 15, cl = tid >> 4;  // 16 p4-groups x 16 c-lanes
#pragma unroll
  for (int it = 0; it < 4; ++it) {
    int c = cl + 16 * it;
    int p = p0 + p4 * 4;
    f4 v = {0.f, 0.f, 0.f, 0.f};
    const float* sp = x + ((size_t)b * C_DIM + c0 + c) * HW;
    if (p + 3 < HW) {
      v = *(const f4*)(sp + p);
    } else {
#pragma unroll
      for (int j = 0; j < 4; ++j) if (p + j < HW) v[j] = sp[p + j];
    }
    t[p4 * 4 + 0][c] = v[0];
    t[p4 * 4 + 1][c] = v[1];
    t[p4 * 4 + 2][c] = v[2];
    t[p4 * 4 + 3][c] = v[3];
  }
  __syncthreads();
  int pl = tid >> 2, cq = tid & 3;
  int p = p0 + pl;
  if (p < HW) {
    half8 h0, h1;
#pragma unroll
    for (int j = 0; j < 8; ++j) {
      h0[j] = (_Float16)t[pl][cq * 16 + j];
      h1[j] = (_Float16)t[pl][cq * 16 + 8 + j];
    }
    _Float16* dst = xt + ((size_t)b * HW + p) * C_DIM + c0 + cq * 16;
    *(half8*)dst = h0;
    *(half8*)(dst + 8) = h1;
  }
}

// ---- WqkT[h][c'][c] f16 = (wq_h^T wk_h)^T * scale ; qkb[h][c'] ------------
__global__ __launch_bounds__(256) void prep_wqk(
    const float* __restrict__ wq, const float* __restrict__ wk,
    const float* __restrict__ bq, _Float16* __restrict__ WqkT,
    float* __restrict__ qkb) {
  int cp = blockIdx.x;  // c'
  int h = blockIdx.y;
  int c = threadIdx.x;
  float acc = 0.f, accb = 0.f;
#pragma unroll 4
  for (int dd = 0; dd < HD; ++dd) {
    float wkv = wk[(size_t)(h * HD + dd) * C_DIM + cp];
    acc += wq[(size_t)(h * HD + dd) * C_DIM + c] * wkv;
    accb += bq[h * HD + dd] * wkv;
  }
  const float s = 0.17677669529663687f;  // 1/sqrt(32)
  WqkT[((size_t)h * C_DIM + cp) * C_DIM + c] = (_Float16)(acc * s);
  if (c == 0) qkb[h * C_DIM + cp] = accb * s;
}

// ---- wv f32 -> f16 --------------------------------------------------------
__global__ __launch_bounds__(256) void prep_wv(
    const float* __restrict__ wv, _Float16* __restrict__ wvh) {
  int i = blockIdx.x * 256 + threadIdx.x;
  wvh[i] = (_Float16)wv[i];
}

// ---- qk_g[bq][h][c'] f16 = q @ WqkT + qkb  (MFMA GEMM) --------------------
__global__ __launch_bounds__(256) void qk_kernel(
    const float* __restrict__ q, const _Float16* __restrict__ WqkT,
    const float* __restrict__ qkb, _Float16* __restrict__ qk_g) {
  int tid = threadIdx.x;
  int lane = tid & 63;
  int wid = tid >> 6;
  int mtile = blockIdx.x, cg = blockIdx.y;
  int m = lane & 15, kq = lane >> 4;
  int bqr = mtile * 16 + m;
  half8 af[8];
  const float* qrow = q + (size_t)bqr * C_DIM + kq * 8;
#pragma unroll
  for (int ks = 0; ks < 8; ++ks) {
    f4 v0 = *(const f4*)(qrow + ks * 32);
    f4 v1 = *(const f4*)(qrow + ks * 32 + 4);
    half8 a;
    a[0] = (_Float16)v0[0]; a[1] = (_Float16)v0[1];
    a[2] = (_Float16)v0[2]; a[3] = (_Float16)v0[3];
    a[4] = (_Float16)v1[0]; a[5] = (_Float16)v1[1];
    a[6] = (_Float16)v1[2]; a[7] = (_Float16)v1[3];
    af[ks] = a;
  }
#pragma unroll 1
  for (int t = 0; t < 8; ++t) {
    int ct = cg * 32 + wid * 8 + t;     // 0..127
    int h = ct >> 4, nt = ct & 15;
    int cp = nt * 16 + m;
    const _Float16* brow = WqkT + ((size_t)h * C_DIM + cp) * C_DIM + kq * 8;
    f4 acc = {0.f, 0.f, 0.f, 0.f};
#pragma unroll
    for (int ks = 0; ks < 8; ++ks) {
      half8 bf = *(const half8*)(brow + ks * 32);
      acc = __builtin_amdgcn_mfma_f32_16x16x32_f16(af[ks], bf, acc, 0, 0, 0);
    }
    float qb = qkb[h * C_DIM + cp];
#pragma unroll
    for (int r = 0; r < 4; ++r) {
      int bqo = mtile * 16 + kq * 4 + r;
      qk_g[((size_t)bqo * NH + h) * C_DIM + cp] = (_Float16)(acc[r] + qb);
    }
  }
}

// ---- fused gather + logits(MFMA) + softmax + pv ---------------------------
__global__ __launch_bounds__(256) void attn_mfma_kernel(
    const _Float16* __restrict__ xt, const float* __restrict__ ref,
    const _Float16* __restrict__ qk_g, _Float16* __restrict__ pv_g) {
  __shared__ __align__(16) _Float16 samp[NS][264];
  __shared__ __align__(16) _Float16 qks[16][264];
  __shared__ float p_s[16][36];

  int tid = threadIdx.x;
  int q2g = blockIdx.x;  // 0..499
  int b = blockIdx.y;
  int q2_0 = q2g * BQ2;
  int m0 = q2g * NS;

  // stage qk rows: pair = q2l*8+h
  {
    int pair = tid >> 4;
    int col = (tid & 15) * 16;
    int qq = q2_0 + (pair >> 3);
    int hh = pair & 7;
    const _Float16* src = qk_g + (((size_t)b * Q_DIM + qq) * NH + hh) * C_DIM + col;
    *(half8*)&qks[pair][col] = *(const half8*)src;
    *(half8*)&qks[pair][col + 8] = *(const half8*)(src + 8);
  }

  // gather: half-wave (32 lanes) per sample
  {
    int s_half = tid >> 5, cl = tid & 31;
    const _Float16* base = xt + (size_t)b * HW * C_DIM + cl * 8;
#pragma unroll 1
    for (int it = 0; it < 4; ++it) {
      int i = it * 8 + s_half;
      int mm = m0 + i;
      int qq = mm % Q_DIM, nn = mm / Q_DIM;
      const float* rp = ref + (((size_t)b * Q_DIM + qq) * N_PTS + nn) * 2;
      float gx = (rp[0] + 1.f) * 50.f - 0.5f;
      float gy = (rp[1] + 1.f) * 50.f - 0.5f;
      float fx0 = floorf(gx), fy0 = floorf(gy);
      float fx = gx - fx0, fy = gy - fy0;
      int ix0 = (int)fx0, iy0 = (int)fy0;
      int ix1 = ix0 + 1, iy1 = iy0 + 1;
      bool x0ok = ix0 >= 0 && ix0 < W_IMG, x1ok = ix1 >= 0 && ix1 < W_IMG;
      bool y0ok = iy0 >= 0 && iy0 < H_IMG, y1ok = iy1 >= 0 && iy1 < H_IMG;
      float acc[8] = {0.f, 0.f, 0.f, 0.f, 0.f, 0.f, 0.f, 0.f};
      if (x0ok && y0ok) {
        half8 v = *(const half8*)(base + (size_t)(iy0 * W_IMG + ix0) * C_DIM);
        float w = (1.f - fx) * (1.f - fy);
#pragma unroll
        for (int j = 0; j < 8; ++j) acc[j] += w * (float)v[j];
      }
      if (x1ok && y0ok) {
        half8 v = *(const half8*)(base + (size_t)(iy0 * W_IMG + ix1) * C_DIM);
        float w = fx * (1.f - fy);
#pragma unroll
        for (int j = 0; j < 8; ++j) acc[j] += w * (float)v[j];
      }
      if (x0ok && y1ok) {
        half8 v = *(const half8*)(base + (size_t)(iy1 * W_IMG + ix0) * C_DIM);
        float w = (1.f - fx) * fy;
#pragma unroll
        for (int j = 0; j < 8; ++j) acc[j] += w * (float)v[j];
      }
      if (x1ok && y1ok) {
        half8 v = *(const half8*)(base + (size_t)(iy1 * W_IMG + ix1) * C_DIM);
        float w = fx * fy;
#pragma unroll
        for (int j = 0; j < 8; ++j) acc[j] += w * (float)v[j];
      }
      half8 o;
#pragma unroll
      for (int j = 0; j < 8; ++j) o[j] = (_Float16)acc[j];
      *(half8*)&samp[i][cl * 8] = o;
    }
  }
  __syncthreads();

  // logits via MFMA on waves 0,1 (wave w: samples of query w), then softmax
  {
    int wid = tid >> 6, lane = tid & 63;
    int m_ = lane & 15, kq = lane >> 4;
    if (wid < 2) {
      f4 d = {0.f, 0.f, 0.f, 0.f};
#pragma unroll
      for (int ks = 0; ks < 8; ++ks) {
        half8 a = *(const half8*)&qks[m_][ks * 32 + kq * 8];
        half8 bfr = *(const half8*)&samp[wid * 16 + m_][ks * 32 + kq * 8];
        d = __builtin_amdgcn_mfma_f32_16x16x32_f16(a, bfr, d, 0, 0, 0);
      }
      // rows pair = kq*4+r (valid iff pair>>3 == wid); cols = sample m_
#pragma unroll
      for (int r = 0; r < 4; ++r) {
        int pair = kq * 4 + r;
        float v = d[r];
        float mx = v;
#pragma unroll
        for (int off = 1; off < 16; off <<= 1) mx = fmaxf(mx, __shfl_xor(mx, off, 16));
        float e = __expf(v - mx);
        float s = e;
#pragma unroll
        for (int off = 1; off < 16; off <<= 1) s += __shfl_xor(s, off, 16);
        if ((pair >> 3) == wid) p_s[pair][wid * 16 + m_] = e / s;
      }
    }
  }
  __syncthreads();

  // pv[pair][c'] = sum_n p * samp ; thread = (chunk of 8 ch, head)
  {
    int chunk = tid & 31, pg = tid >> 5;  // pg = head
    float accA[8] = {0.f, 0.f, 0.f, 0.f, 0.f, 0.f, 0.f, 0.f};
    float accB[8] = {0.f, 0.f, 0.f, 0.f, 0.f, 0.f, 0.f, 0.f};
#pragma unroll 4
    for (int n = 0; n < 16; ++n) {
      half8 s0 = *(const half8*)&samp[n][chunk * 8];
      half8 s1 = *(const half8*)&samp[16 + n][chunk * 8];
      float pA = p_s[pg][n];
      float pB = p_s[pg + 8][16 + n];
#pragma unroll
      for (int j = 0; j < 8; ++j) {
        accA[j] += pA * (float)s0[j];
        accB[j] += pB * (float)s1[j];
      }
    }
    half8 oA, oB;
#pragma unroll
    for (int j = 0; j < 8; ++j) {
      oA[j] = (_Float16)accA[j];
      oB[j] = (_Float16)accB[j];
    }
    _Float16* dst = pv_g + (((size_t)b * Q_DIM + q2_0) * NH + pg) * C_DIM + chunk * 8;
    *(half8*)dst = oA;
    *(half8*)(dst + (size_t)NH * C_DIM) = oB;
  }
}

// ---- out[bq][c] f32 = pv_h @ wv_h^T + bv  (per-head MFMA GEMM) ------------
__global__ __launch_bounds__(256) void proj_kernel(
    const _Float16* __restrict__ pv_g, const _Float16* __restrict__ wvh,
    const float* __restrict__ bv, float* __restrict__ out) {
  int tid = threadIdx.x, lane = tid & 63, wid = tid >> 6;
  int mtile = blockIdx.x;
  int m = lane & 15, kq = lane >> 4;
#pragma unroll 1
  for (int hh = 0; hh < 2; ++hh) {
    int h = wid * 2 + hh;
    half8 af[8];
    const _Float16* arow = pv_g + ((size_t)(mtile * 16 + m) * NH + h) * C_DIM + kq * 8;
#pragma unroll
    for (int ks = 0; ks < 8; ++ks) af[ks] = *(const half8*)(arow + ks * 32);
#pragma unroll 1
    for (int nt = 0; nt < 2; ++nt) {
      int c = h * 32 + nt * 16 + m;
      const _Float16* brow = wvh + (size_t)c * C_DIM + kq * 8;
      f4 acc = {0.f, 0.f, 0.f, 0.f};
#pragma unroll
      for (int ks = 0; ks < 8; ++ks)
        acc = __builtin_amdgcn_mfma_f32_16x16x32_f16(af[ks], *(const half8*)(brow + ks * 32),
                                                     acc, 0, 0, 0);
      float bvv = bv[c];
#pragma unroll
      for (int r = 0; r < 4; ++r)
        out[(size_t)(mtile * 16 + kq * 4 + r) * C_DIM + c] = acc[r] + bvv;
    }
  }
}

// ===========================================================================
// FALLBACK PATH (round-2 fp32 kernels, used only if workspace is too small)
// ===========================================================================
__global__ __launch_bounds__(256) void transpose_kernel(
    const float* __restrict__ in, float* __restrict__ out, int rows, int cols) {
  __shared__ float t[32][33];
  size_t off = (size_t)blockIdx.z * rows * cols;
  int r0 = blockIdx.y * 32, c0 = blockIdx.x * 32;
  int tx = threadIdx.x, ty = threadIdx.y;
#pragma unroll
  for (int k = 0; k < 4; ++k) {
    int r = r0 + ty + 8 * k, c = c0 + tx;
    if (r < rows && c < cols) t[ty + 8 * k][tx] = in[off + (size_t)r * cols + c];
  }
  __syncthreads();
#pragma unroll
  for (int k = 0; k < 4; ++k) {
    int c = c0 + ty + 8 * k, r = r0 + tx;
    if (r < rows && c < cols) out[off + (size_t)c * rows + r] = t[tx][ty + 8 * k];
  }
}

__global__ __launch_bounds__(256) void qp_kernel(
    const float* __restrict__ q, const float* __restrict__ wq,
    const float* __restrict__ bq, float* __restrict__ qp) {
  __shared__ float qrows[16][257];
  int row0 = blockIdx.x * 16;
  int tid = threadIdx.x;
  for (int t = tid; t < 16 * C_DIM; t += 256) {
    int r = t >> 8, c = t & 255;
    qrows[r][c] = q[(size_t)(row0 + r) * C_DIM + c];
  }
  __syncthreads();
  float acc[16];
  float b0 = bq[tid];
#pragma unroll
  for (int r = 0; r < 16; ++r) acc[r] = b0;
  const float* wrow = wq + (size_t)tid * C_DIM;
  for (int cc = 0; cc < C_DIM; ++cc) {
    float w = wrow[cc];
#pragma unroll
    for (int r = 0; r < 16; ++r) acc[r] += qrows[r][cc] * w;
  }
#pragma unroll
  for (int r = 0; r < 16; ++r) qp[(size_t)(row0 + r) * C_DIM + tid] = acc[r];
}

__global__ __launch_bounds__(256) void attn_fb_kernel(
    const float* __restrict__ src, int strB, int strY, int strX, int strC,
    const float* __restrict__ ref, const float* __restrict__ qp,
    const float* __restrict__ q, const float* __restrict__ wq,
    const float* __restrict__ bq, const float* __restrict__ wk,
    const float* __restrict__ wv, const float* __restrict__ bv,
    float* __restrict__ out) {
  __shared__ __align__(16) float qp_s[BQ2][C_DIM];
  __shared__ __align__(16) float qk_s[16][260];
  __shared__ __align__(16) float samp_f[NS][260];
  __shared__ float p_f[16][16];
  __shared__ float logit_s[256];

  int tid = threadIdx.x;
  int q2g = blockIdx.x;
  int b = blockIdx.y;
  int q2_0 = q2g * BQ2;
  int m0 = q2g * NS;
  int c4 = tid & 63;
  int grp = tid >> 6;

  if (qp) {
    if (tid < 128) {
      int r = tid >> 6, cc4 = tid & 63;
      *(f4*)&qp_s[r][cc4 * 4] =
          *(const f4*)(qp + ((size_t)b * Q_DIM + q2_0 + r) * C_DIM + cc4 * 4);
    }
  } else {
#pragma unroll
    for (int r = 0; r < BQ2; ++r) {
      float acc = bq[tid];
      const float* qrow = q + ((size_t)b * Q_DIM + q2_0 + r) * C_DIM;
      const float* wrow = wq + (size_t)tid * C_DIM;
      for (int cc = 0; cc < C_DIM; ++cc) acc += qrow[cc] * wrow[cc];
      qp_s[r][tid] = acc;
    }
  }

  {
    int coff = tid * strC;
#pragma unroll 1
    for (int i = 0; i < NS; ++i) {
      int mm = m0 + i;
      int qq = mm % Q_DIM;
      int nn = mm / Q_DIM;
      const float* rp = ref + (((size_t)b * Q_DIM + qq) * N_PTS + nn) * 2;
      float gx = (rp[0] + 1.f) * 50.f - 0.5f;
      float gy = (rp[1] + 1.f) * 50.f - 0.5f;
      float fx0 = floorf(gx), fy0 = floorf(gy);
      float fx = gx - fx0, fy = gy - fy0;
      int ix0 = (int)fx0, iy0 = (int)fy0;
      int ix1 = ix0 + 1, iy1 = iy0 + 1;
      float w00 = (1.f - fx) * (1.f - fy);
      float w01 = fx * (1.f - fy);
      float w10 = (1.f - fx) * fy;
      float w11 = fx * fy;
      size_t bse = (size_t)(b * strB + coff);
      float v = 0.f;
      if (ix0 >= 0 && ix0 < W_IMG) {
        if (iy0 >= 0 && iy0 < H_IMG) v += w00 * src[bse + (size_t)iy0 * strY + (size_t)ix0 * strX];
        if (iy1 >= 0 && iy1 < H_IMG) v += w10 * src[bse + (size_t)iy1 * strY + (size_t)ix0 * strX];
      }
      if (ix1 >= 0 && ix1 < W_IMG) {
        if (iy0 >= 0 && iy0 < H_IMG) v += w01 * src[bse + (size_t)iy0 * strY + (size_t)ix1 * strX];
        if (iy1 >= 0 && iy1 < H_IMG) v += w11 * src[bse + (size_t)iy1 * strY + (size_t)ix1 * strX];
      }
      samp_f[i][tid] = v;
    }
  }
  __syncthreads();

#pragma unroll 1
  for (int hh = 0; hh < 2; ++hh) {
    int h = grp * 2 + hh;
    f4 acc0 = {0.f, 0.f, 0.f, 0.f};
    f4 acc1 = {0.f, 0.f, 0.f, 0.f};
#pragma unroll 2
    for (int dd4 = 0; dd4 < 8; ++dd4) {
      f4 a0 = *(const f4*)&qp_s[0][h * HD + dd4 * 4];
      f4 a1 = *(const f4*)&qp_s[1][h * HD + dd4 * 4];
#pragma unroll
      for (int j = 0; j < 4; ++j) {
        f4 w4 = *(const f4*)(wk + (size_t)(h * HD + dd4 * 4 + j) * C_DIM + c4 * 4);
        acc0 += a0[j] * w4;
        acc1 += a1[j] * w4;
      }
    }
    *(f4*)&qk_s[h][c4 * 4] = acc0;
    *(f4*)&qk_s[8 + h][c4 * 4] = acc1;
  }
  __syncthreads();

  {
    int pair = tid >> 4;
    int n2 = tid & 15;
    int i = (pair >> 3) * 16 + n2;
    float acc = 0.f;
#pragma unroll 4
    for (int cc4 = 0; cc4 < 64; ++cc4) {
      f4 qk4 = *(const f4*)&qk_s[pair][cc4 * 4];
      f4 s4 = *(const f4*)&samp_f[i][cc4 * 4];
      acc += qk4[0] * s4[0] + qk4[1] * s4[1] + qk4[2] * s4[2] + qk4[3] * s4[3];
    }
    logit_s[tid] = acc * 0.17677669529663687f;
  }
  __syncthreads();

  if (tid < 16) {
    float mx = -1e30f;
#pragma unroll
    for (int n2 = 0; n2 < 16; ++n2) mx = fmaxf(mx, logit_s[tid * 16 + n2]);
    float s = 0.f;
    float e[16];
#pragma unroll
    for (int n2 = 0; n2 < 16; ++n2) {
      e[n2] = __expf(logit_s[tid * 16 + n2] - mx);
      s += e[n2];
    }
    float inv = 1.f / s;
#pragma unroll
    for (int n2 = 0; n2 < 16; ++n2) p_f[tid][n2] = e[n2] * inv;
  }
  __syncthreads();

#pragma unroll 1
  for (int k = 0; k < 4; ++k) {
    int pair = k * 4 + grp;
    int roff = (pair >> 3) * 16;
    f4 acc = {0.f, 0.f, 0.f, 0.f};
#pragma unroll
    for (int n2 = 0; n2 < 16; ++n2)
      acc += p_f[pair][n2] * *(const f4*)&samp_f[roff + n2][c4 * 4];
    *(f4*)&qk_s[pair][c4 * 4] = acc;
  }
  __syncthreads();

  {
    int h = tid >> 5;
    float acc0 = 0.f, acc1 = 0.f;
#pragma unroll 4
    for (int cc4 = 0; cc4 < 64; ++cc4) {
      f4 pv0 = *(const f4*)&qk_s[h][cc4 * 4];
      f4 pv1 = *(const f4*)&qk_s[8 + h][cc4 * 4];
      f4 w4 = *(const f4*)(wv + (size_t)tid * C_DIM + cc4 * 4);
      acc0 += pv0[0] * w4[0] + pv0[1] * w4[1] + pv0[2] * w4[2] + pv0[3] * w4[3];
      acc1 += pv1[0] * w4[0] + pv1[1] * w4[1] + pv1[2] * w4[2] + pv1[3] * w4[3];
    }
    float bvv = bv[tid];
    out[((size_t)b * Q_DIM + q2_0) * C_DIM + tid] = acc0 + bvv;
    out[((size_t)b * Q_DIM + q2_0 + 1) * C_DIM + tid] = acc1 + bvv;
  }
}

// ===========================================================================
extern "C" void kernel_launch(void* const* d_in, const int* in_sizes, int n_in,
                              void* d_out, int out_size, void* d_ws, size_t ws_size,
                              hipStream_t stream) {
  const float* x   = (const float*)d_in[0];
  const float* q   = (const float*)d_in[1];
  const float* ref = (const float*)d_in[2];
  const float* wq  = (const float*)d_in[3];
  const float* bq  = (const float*)d_in[4];
  const float* wk  = (const float*)d_in[5];
  // d_in[6] = bk: provably cancels in softmax (constant shift per row)
  const float* wv  = (const float*)d_in[7];
  const float* bv  = (const float*)d_in[8];
  float* out = (float*)d_out;

  const size_t XT_B   = (size_t)B_DIM * HW * C_DIM * 2;          // 81.92 MB
  const size_t QK_B   = (size_t)B_DIM * Q_DIM * NH * C_DIM * 2;  // 65.5 MB
  const size_t PV_B   = QK_B;                                    // 65.5 MB
  const size_t WQKT_B = (size_t)NH * C_DIM * C_DIM * 2;          // 1 MB
  const size_t QKB_B  = (size_t)NH * C_DIM * 4;                  // 8 KB
  const size_t WVH_B  = (size_t)C_DIM * C_DIM * 2;               // 128 KB
  const size_t NEED   = XT_B + QK_B + PV_B + WQKT_B + QKB_B + WVH_B;

  if (ws_size >= NEED) {
    char* p = (char*)d_ws;
    _Float16* xt   = (_Float16*)p;            p += XT_B;
    _Float16* qk_g = (_Float16*)p;            p += QK_B;
    _Float16* pv_g = (_Float16*)p;            p += PV_B;
    _Float16* WqkT = (_Float16*)p;            p += WQKT_B;
    float*    qkb  = (float*)p;               p += QKB_B;
    _Float16* wvh  = (_Float16*)p;

    xt_kernel<<<dim3((HW + 63) / 64, C_DIM / 64, B_DIM), 256, 0, stream>>>(x, xt);
    prep_wqk<<<dim3(C_DIM, NH), 256, 0, stream>>>(wq, wk, bq, WqkT, qkb);
    prep_wv<<<C_DIM * C_DIM / 256, 256, 0, stream>>>(wv, wvh);
    qk_kernel<<<dim3(B_DIM * Q_DIM / 16, 4), 256, 0, stream>>>(q, WqkT, qkb, qk_g);
    attn_mfma_kernel<<<dim3(Q_DIM / BQ2, B_DIM), 256, 0, stream>>>(xt, ref, qk_g, pv_g);
    proj_kernel<<<B_DIM * Q_DIM / 16, 256, 0, stream>>>(pv_g, wvh, bv, out);
  } else {
    // fallback: round-2 fp32 path
    const size_t QP_BYTES = (size_t)B_DIM * Q_DIM * C_DIM * 4;
    const size_t XTF_BYTES = (size_t)B_DIM * HW * C_DIM * 4;
    float* qp = nullptr;
    float* xtf = nullptr;
    if (ws_size >= QP_BYTES) qp = (float*)d_ws;
    if (ws_size >= QP_BYTES + XTF_BYTES) xtf = (float*)((char*)d_ws + QP_BYTES);

    if (xtf) {
      dim3 g((HW + 31) / 32, C_DIM / 32, B_DIM);
      transpose_kernel<<<g, dim3(32, 8), 0, stream>>>(x, xtf, C_DIM, HW);
    }
    if (qp) qp_kernel<<<B_DIM * Q_DIM / 16, 256, 0, stream>>>(q, wq, bq, qp);

    const float* src;
    int sB, sY, sX, sC;
    if (xtf) { src = xtf; sB = HW * C_DIM; sY = W_IMG * C_DIM; sX = C_DIM; sC = 1; }
    else     { src = x;   sB = C_DIM * HW; sY = W_IMG;         sX = 1;     sC = HW; }

    attn_fb_kernel<<<dim3(Q_DIM / BQ2, B_DIM), 256, 0, stream>>>(
        src, sB, sY, sX, sC, ref, qp, q, wq, bq, wk, wv, bv, out);
  }
}

// Round 4
// 455.480 us; speedup vs baseline: 3.3287x; 1.2318x over previous
//
#include <hip/hip_runtime.h>
#include <math.h>

typedef float f4 __attribute__((ext_vector_type(4)));
typedef _Float16 half8 __attribute__((ext_vector_type(8)));

#define C_DIM 256
#define NH 8
#define HD 32
#define Q_DIM 1000
#define N_PTS 16
#define B_DIM 16
#define H_IMG 100
#define W_IMG 100
#define HW 10000
#define BQ2 2
#define NS 32
#define N_QK 2048   // NH * C_DIM

// ===========================================================================
// NEW PATH (f16 + MFMA)
// ===========================================================================

// ---- x [B,C,HW] f32 -> xt [B,HW,C] f16 ------------------------------------
__global__ __launch_bounds__(256) void xt_kernel(
    const float* __restrict__ x, _Float16* __restrict__ xt) {
  __shared__ float t[64][65];
  int p0 = blockIdx.x * 64;
  int c0 = blockIdx.y * 64;
  int b = blockIdx.z;
  int tid = threadIdx.x;
  int p4 = tid & 15, cl = tid >> 4;
#pragma unroll
  for (int it = 0; it < 4; ++it) {
    int c = cl + 16 * it;
    int p = p0 + p4 * 4;
    f4 v = {0.f, 0.f, 0.f, 0.f};
    const float* sp = x + ((size_t)b * C_DIM + c0 + c) * HW;
    if (p + 3 < HW) {
      v = *(const f4*)(sp + p);
    } else {
#pragma unroll
      for (int j = 0; j < 4; ++j) if (p + j < HW) v[j] = sp[p + j];
    }
    t[p4 * 4 + 0][c] = v[0];
    t[p4 * 4 + 1][c] = v[1];
    t[p4 * 4 + 2][c] = v[2];
    t[p4 * 4 + 3][c] = v[3];
  }
  __syncthreads();
  int pl = tid >> 2, cq = tid & 3;
  int p = p0 + pl;
  if (p < HW) {
    half8 h0, h1;
#pragma unroll
    for (int j = 0; j < 8; ++j) {
      h0[j] = (_Float16)t[pl][cq * 16 + j];
      h1[j] = (_Float16)t[pl][cq * 16 + 8 + j];
    }
    _Float16* dst = xt + ((size_t)b * HW + p) * C_DIM + c0 + cq * 16;
    *(half8*)dst = h0;
    *(half8*)(dst + 8) = h1;
  }
}

// ---- q f32 -> f16 ---------------------------------------------------------
__global__ __launch_bounds__(256) void qconv_kernel(
    const float* __restrict__ q, _Float16* __restrict__ qh) {
  size_t i = ((size_t)blockIdx.x * 256 + threadIdx.x) * 8;
  f4 v0 = *(const f4*)(q + i);
  f4 v1 = *(const f4*)(q + i + 4);
  half8 h;
  h[0] = (_Float16)v0[0]; h[1] = (_Float16)v0[1];
  h[2] = (_Float16)v0[2]; h[3] = (_Float16)v0[3];
  h[4] = (_Float16)v1[0]; h[5] = (_Float16)v1[1];
  h[6] = (_Float16)v1[2]; h[7] = (_Float16)v1[3];
  *(half8*)(qh + i) = h;
}

// ---- wqkB[n][c] f16 = s * sum_dd wq[h*HD+dd][c] * wk[h*HD+dd][cp] ---------
// n = h*256 + cp.  Also qkb[n] = s * sum_dd bq[h*HD+dd] * wk[h*HD+dd][cp].
__global__ __launch_bounds__(256) void prep_wqk(
    const float* __restrict__ wq, const float* __restrict__ wk,
    const float* __restrict__ bq, _Float16* __restrict__ wqkB,
    float* __restrict__ qkb) {
  int n = blockIdx.x;
  int h = n >> 8, cp = n & 255;
  int c = threadIdx.x;
  float acc = 0.f, accb = 0.f;
#pragma unroll 4
  for (int dd = 0; dd < HD; ++dd) {
    float wkv = wk[(size_t)(h * HD + dd) * C_DIM + cp];
    acc += wq[(size_t)(h * HD + dd) * C_DIM + c] * wkv;
    accb += bq[h * HD + dd] * wkv;
  }
  const float s = 0.17677669529663687f;  // 1/sqrt(32)
  wqkB[(size_t)n * C_DIM + c] = (_Float16)(acc * s);
  if (c == 0) qkb[n] = accb * s;
}

// ---- wv f32 -> f16 --------------------------------------------------------
__global__ __launch_bounds__(256) void prep_wv(
    const float* __restrict__ wv, _Float16* __restrict__ wvh) {
  int i = blockIdx.x * 256 + threadIdx.x;
  wvh[i] = (_Float16)wv[i];
}

// ---- qk_g[m][n] f16 = qh[m][k] @ wqkB[n][k]^T + qkb[n]  (tiled MFMA) ------
// M=16000, N=2048, K=256. BM=BN=128, BK=64. 4 waves, each 64x64 (4x4 tiles).
__global__ __launch_bounds__(256) void qk_gemm(
    const _Float16* __restrict__ qh, const _Float16* __restrict__ wqkB,
    const float* __restrict__ qkb, _Float16* __restrict__ qk_g) {
  __shared__ __align__(16) _Float16 lds_buf[2 * 128 * 72];  // 36.9 KB
  _Float16* As = lds_buf;             // [128][72]
  _Float16* Bs = lds_buf + 128 * 72;  // [128][72]

  int tid = threadIdx.x;
  int m0 = blockIdx.x * 128;
  int n0 = blockIdx.y * 128;
  int wid = tid >> 6, lane = tid & 63;
  int wm = wid >> 1, wn = wid & 1;
  int m_ = lane & 15, kq = lane >> 4;

  f4 acc[4][4];
#pragma unroll
  for (int i = 0; i < 4; ++i)
#pragma unroll
    for (int j = 0; j < 4; ++j) acc[i][j] = {0.f, 0.f, 0.f, 0.f};

#pragma unroll 1
  for (int k0 = 0; k0 < C_DIM; k0 += 64) {
    if (k0) __syncthreads();
#pragma unroll
    for (int j = 0; j < 4; ++j) {
      int idx = j * 256 + tid;
      int r = idx >> 3, kc = idx & 7;
      *(half8*)&As[r * 72 + kc * 8] =
          *(const half8*)(qh + (size_t)(m0 + r) * C_DIM + k0 + kc * 8);
      *(half8*)&Bs[r * 72 + kc * 8] =
          *(const half8*)(wqkB + (size_t)(n0 + r) * C_DIM + k0 + kc * 8);
    }
    __syncthreads();
#pragma unroll
    for (int kk = 0; kk < 64; kk += 32) {
      half8 af[4], bf[4];
#pragma unroll
      for (int mt = 0; mt < 4; ++mt)
        af[mt] = *(const half8*)&As[(wm * 64 + mt * 16 + m_) * 72 + kk + kq * 8];
#pragma unroll
      for (int nt = 0; nt < 4; ++nt)
        bf[nt] = *(const half8*)&Bs[(wn * 64 + nt * 16 + m_) * 72 + kk + kq * 8];
#pragma unroll
      for (int mt = 0; mt < 4; ++mt)
#pragma unroll
        for (int nt = 0; nt < 4; ++nt)
          acc[mt][nt] = __builtin_amdgcn_mfma_f32_16x16x32_f16(
              af[mt], bf[nt], acc[mt][nt], 0, 0, 0);
    }
  }

  // epilogue: C + qkb through LDS, then coalesced half8 stores
  __syncthreads();
  _Float16* Cs = lds_buf;  // [128][136] = 34.8 KB
#pragma unroll
  for (int nt = 0; nt < 4; ++nt) {
    int col_l = wn * 64 + nt * 16 + m_;
    float qb = qkb[n0 + col_l];
#pragma unroll
    for (int mt = 0; mt < 4; ++mt) {
      int row_b = wm * 64 + mt * 16 + kq * 4;
#pragma unroll
      for (int r = 0; r < 4; ++r)
        Cs[(row_b + r) * 136 + col_l] = (_Float16)(acc[mt][nt][r] + qb);
    }
  }
  __syncthreads();
#pragma unroll
  for (int j = 0; j < 8; ++j) {
    int idx = j * 256 + tid;
    int r = idx >> 4, cc = idx & 15;
    *(half8*)(qk_g + (size_t)(m0 + r) * N_QK + n0 + cc * 8) =
        *(const half8*)&Cs[r * 136 + cc * 8];
  }
}

// ---- fused gather + logits(MFMA) + softmax + pv ---------------------------
__global__ __launch_bounds__(256) void attn_mfma_kernel(
    const _Float16* __restrict__ xt, const float* __restrict__ ref,
    const _Float16* __restrict__ qk_g, _Float16* __restrict__ pv_g) {
  __shared__ __align__(16) _Float16 samp[NS][264];
  __shared__ __align__(16) _Float16 qks[16][264];
  __shared__ float p_s[16][36];

  int tid = threadIdx.x;
  int q2g = blockIdx.x;
  int b = blockIdx.y;
  int q2_0 = q2g * BQ2;
  int m0 = q2g * NS;

  // stage qk rows: pair = q2l*8+h ; qk_g row = b*Q_DIM+qq, cols h*256..
  {
    int pair = tid >> 4;
    int col = (tid & 15) * 16;
    int qq = q2_0 + (pair >> 3);
    int hh = pair & 7;
    const _Float16* src = qk_g + ((size_t)b * Q_DIM + qq) * N_QK + hh * C_DIM + col;
    *(half8*)&qks[pair][col] = *(const half8*)src;
    *(half8*)&qks[pair][col + 8] = *(const half8*)(src + 8);
  }

  // gather: half-wave (32 lanes) per sample
  {
    int s_half = tid >> 5, cl = tid & 31;
    const _Float16* base = xt + (size_t)b * HW * C_DIM + cl * 8;
#pragma unroll 1
    for (int it = 0; it < 4; ++it) {
      int i = it * 8 + s_half;
      int mm = m0 + i;
      int qq = mm % Q_DIM, nn = mm / Q_DIM;
      const float* rp = ref + (((size_t)b * Q_DIM + qq) * N_PTS + nn) * 2;
      float gx = (rp[0] + 1.f) * 50.f - 0.5f;
      float gy = (rp[1] + 1.f) * 50.f - 0.5f;
      float fx0 = floorf(gx), fy0 = floorf(gy);
      float fx = gx - fx0, fy = gy - fy0;
      int ix0 = (int)fx0, iy0 = (int)fy0;
      int ix1 = ix0 + 1, iy1 = iy0 + 1;
      bool x0ok = ix0 >= 0 && ix0 < W_IMG, x1ok = ix1 >= 0 && ix1 < W_IMG;
      bool y0ok = iy0 >= 0 && iy0 < H_IMG, y1ok = iy1 >= 0 && iy1 < H_IMG;
      float acc[8] = {0.f, 0.f, 0.f, 0.f, 0.f, 0.f, 0.f, 0.f};
      if (x0ok && y0ok) {
        half8 v = *(const half8*)(base + (size_t)(iy0 * W_IMG + ix0) * C_DIM);
        float w = (1.f - fx) * (1.f - fy);
#pragma unroll
        for (int j = 0; j < 8; ++j) acc[j] += w * (float)v[j];
      }
      if (x1ok && y0ok) {
        half8 v = *(const half8*)(base + (size_t)(iy0 * W_IMG + ix1) * C_DIM);
        float w = fx * (1.f - fy);
#pragma unroll
        for (int j = 0; j < 8; ++j) acc[j] += w * (float)v[j];
      }
      if (x0ok && y1ok) {
        half8 v = *(const half8*)(base + (size_t)(iy1 * W_IMG + ix0) * C_DIM);
        float w = (1.f - fx) * fy;
#pragma unroll
        for (int j = 0; j < 8; ++j) acc[j] += w * (float)v[j];
      }
      if (x1ok && y1ok) {
        half8 v = *(const half8*)(base + (size_t)(iy1 * W_IMG + ix1) * C_DIM);
        float w = fx * fy;
#pragma unroll
        for (int j = 0; j < 8; ++j) acc[j] += w * (float)v[j];
      }
      half8 o;
#pragma unroll
      for (int j = 0; j < 8; ++j) o[j] = (_Float16)acc[j];
      *(half8*)&samp[i][cl * 8] = o;
    }
  }
  __syncthreads();

  // logits via MFMA on waves 0,1 then softmax via shfl
  {
    int wid = tid >> 6, lane = tid & 63;
    int m_ = lane & 15, kq = lane >> 4;
    if (wid < 2) {
      f4 d = {0.f, 0.f, 0.f, 0.f};
#pragma unroll
      for (int ks = 0; ks < 8; ++ks) {
        half8 a = *(const half8*)&qks[m_][ks * 32 + kq * 8];
        half8 bfr = *(const half8*)&samp[wid * 16 + m_][ks * 32 + kq * 8];
        d = __builtin_amdgcn_mfma_f32_16x16x32_f16(a, bfr, d, 0, 0, 0);
      }
#pragma unroll
      for (int r = 0; r < 4; ++r) {
        int pair = kq * 4 + r;
        float v = d[r];
        float mx = v;
#pragma unroll
        for (int off = 1; off < 16; off <<= 1) mx = fmaxf(mx, __shfl_xor(mx, off, 16));
        float e = __expf(v - mx);
        float s = e;
#pragma unroll
        for (int off = 1; off < 16; off <<= 1) s += __shfl_xor(s, off, 16);
        if ((pair >> 3) == wid) p_s[pair][wid * 16 + m_] = e / s;
      }
    }
  }
  __syncthreads();

  // pv[pair][c'] = sum_n p * samp
  {
    int chunk = tid & 31, pg = tid >> 5;
    float accA[8] = {0.f, 0.f, 0.f, 0.f, 0.f, 0.f, 0.f, 0.f};
    float accB[8] = {0.f, 0.f, 0.f, 0.f, 0.f, 0.f, 0.f, 0.f};
#pragma unroll 4
    for (int n = 0; n < 16; ++n) {
      half8 s0 = *(const half8*)&samp[n][chunk * 8];
      half8 s1 = *(const half8*)&samp[16 + n][chunk * 8];
      float pA = p_s[pg][n];
      float pB = p_s[pg + 8][16 + n];
#pragma unroll
      for (int j = 0; j < 8; ++j) {
        accA[j] += pA * (float)s0[j];
        accB[j] += pB * (float)s1[j];
      }
    }
    half8 oA, oB;
#pragma unroll
    for (int j = 0; j < 8; ++j) {
      oA[j] = (_Float16)accA[j];
      oB[j] = (_Float16)accB[j];
    }
    _Float16* dst = pv_g + (((size_t)b * Q_DIM + q2_0) * NH + pg) * C_DIM + chunk * 8;
    *(half8*)dst = oA;
    *(half8*)(dst + (size_t)NH * C_DIM) = oB;
  }
}

// ---- out[bq][c] f32 = pv_h @ wv_h^T + bv  (per-head MFMA GEMM) ------------
__global__ __launch_bounds__(256) void proj_kernel(
    const _Float16* __restrict__ pv_g, const _Float16* __restrict__ wvh,
    const float* __restrict__ bv, float* __restrict__ out) {
  int tid = threadIdx.x, lane = tid & 63, wid = tid >> 6;
  int mtile = blockIdx.x;
  int m = lane & 15, kq = lane >> 4;
#pragma unroll 1
  for (int hh = 0; hh < 2; ++hh) {
    int h = wid * 2 + hh;
    half8 af[8];
    const _Float16* arow = pv_g + ((size_t)(mtile * 16 + m) * NH + h) * C_DIM + kq * 8;
#pragma unroll
    for (int ks = 0; ks < 8; ++ks) af[ks] = *(const half8*)(arow + ks * 32);
#pragma unroll 1
    for (int nt = 0; nt < 2; ++nt) {
      int c = h * 32 + nt * 16 + m;
      const _Float16* brow = wvh + (size_t)c * C_DIM + kq * 8;
      f4 acc = {0.f, 0.f, 0.f, 0.f};
#pragma unroll
      for (int ks = 0; ks < 8; ++ks)
        acc = __builtin_amdgcn_mfma_f32_16x16x32_f16(af[ks], *(const half8*)(brow + ks * 32),
                                                     acc, 0, 0, 0);
      float bvv = bv[c];
#pragma unroll
      for (int r = 0; r < 4; ++r)
        out[(size_t)(mtile * 16 + kq * 4 + r) * C_DIM + c] = acc[r] + bvv;
    }
  }
}

// ===========================================================================
// FALLBACK PATH (fp32, used only if workspace is too small)
// ===========================================================================
__global__ __launch_bounds__(256) void transpose_kernel(
    const float* __restrict__ in, float* __restrict__ out, int rows, int cols) {
  __shared__ float t[32][33];
  size_t off = (size_t)blockIdx.z * rows * cols;
  int r0 = blockIdx.y * 32, c0 = blockIdx.x * 32;
  int tx = threadIdx.x, ty = threadIdx.y;
#pragma unroll
  for (int k = 0; k < 4; ++k) {
    int r = r0 + ty + 8 * k, c = c0 + tx;
    if (r < rows && c < cols) t[ty + 8 * k][tx] = in[off + (size_t)r * cols + c];
  }
  __syncthreads();
#pragma unroll
  for (int k = 0; k < 4; ++k) {
    int c = c0 + ty + 8 * k, r = r0 + tx;
    if (r < rows && c < cols) out[off + (size_t)c * rows + r] = t[tx][ty + 8 * k];
  }
}

__global__ __launch_bounds__(256) void qp_kernel(
    const float* __restrict__ q, const float* __restrict__ wq,
    const float* __restrict__ bq, float* __restrict__ qp) {
  __shared__ float qrows[16][257];
  int row0 = blockIdx.x * 16;
  int tid = threadIdx.x;
  for (int t = tid; t < 16 * C_DIM; t += 256) {
    int r = t >> 8, c = t & 255;
    qrows[r][c] = q[(size_t)(row0 + r) * C_DIM + c];
  }
  __syncthreads();
  float acc[16];
  float b0 = bq[tid];
#pragma unroll
  for (int r = 0; r < 16; ++r) acc[r] = b0;
  const float* wrow = wq + (size_t)tid * C_DIM;
  for (int cc = 0; cc < C_DIM; ++cc) {
    float w = wrow[cc];
#pragma unroll
    for (int r = 0; r < 16; ++r) acc[r] += qrows[r][cc] * w;
  }
#pragma unroll
  for (int r = 0; r < 16; ++r) qp[(size_t)(row0 + r) * C_DIM + tid] = acc[r];
}

__global__ __launch_bounds__(256) void attn_fb_kernel(
    const float* __restrict__ src, int strB, int strY, int strX, int strC,
    const float* __restrict__ ref, const float* __restrict__ qp,
    const float* __restrict__ q, const float* __restrict__ wq,
    const float* __restrict__ bq, const float* __restrict__ wk,
    const float* __restrict__ wv, const float* __restrict__ bv,
    float* __restrict__ out) {
  __shared__ __align__(16) float qp_s[BQ2][C_DIM];
  __shared__ __align__(16) float qk_s[16][260];
  __shared__ __align__(16) float samp_f[NS][260];
  __shared__ float p_f[16][16];
  __shared__ float logit_s[256];

  int tid = threadIdx.x;
  int q2g = blockIdx.x;
  int b = blockIdx.y;
  int q2_0 = q2g * BQ2;
  int m0 = q2g * NS;
  int c4 = tid & 63;
  int grp = tid >> 6;

  if (qp) {
    if (tid < 128) {
      int r = tid >> 6, cc4 = tid & 63;
      *(f4*)&qp_s[r][cc4 * 4] =
          *(const f4*)(qp + ((size_t)b * Q_DIM + q2_0 + r) * C_DIM + cc4 * 4);
    }
  } else {
#pragma unroll
    for (int r = 0; r < BQ2; ++r) {
      float acc = bq[tid];
      const float* qrow = q + ((size_t)b * Q_DIM + q2_0 + r) * C_DIM;
      const float* wrow = wq + (size_t)tid * C_DIM;
      for (int cc = 0; cc < C_DIM; ++cc) acc += qrow[cc] * wrow[cc];
      qp_s[r][tid] = acc;
    }
  }

  {
    int coff = tid * strC;
#pragma unroll 1
    for (int i = 0; i < NS; ++i) {
      int mm = m0 + i;
      int qq = mm % Q_DIM;
      int nn = mm / Q_DIM;
      const float* rp = ref + (((size_t)b * Q_DIM + qq) * N_PTS + nn) * 2;
      float gx = (rp[0] + 1.f) * 50.f - 0.5f;
      float gy = (rp[1] + 1.f) * 50.f - 0.5f;
      float fx0 = floorf(gx), fy0 = floorf(gy);
      float fx = gx - fx0, fy = gy - fy0;
      int ix0 = (int)fx0, iy0 = (int)fy0;
      int ix1 = ix0 + 1, iy1 = iy0 + 1;
      float w00 = (1.f - fx) * (1.f - fy);
      float w01 = fx * (1.f - fy);
      float w10 = (1.f - fx) * fy;
      float w11 = fx * fy;
      size_t bse = (size_t)(b * strB + coff);
      float v = 0.f;
      if (ix0 >= 0 && ix0 < W_IMG) {
        if (iy0 >= 0 && iy0 < H_IMG) v += w00 * src[bse + (size_t)iy0 * strY + (size_t)ix0 * strX];
        if (iy1 >= 0 && iy1 < H_IMG) v += w10 * src[bse + (size_t)iy1 * strY + (size_t)ix0 * strX];
      }
      if (ix1 >= 0 && ix1 < W_IMG) {
        if (iy0 >= 0 && iy0 < H_IMG) v += w01 * src[bse + (size_t)iy0 * strY + (size_t)ix1 * strX];
        if (iy1 >= 0 && iy1 < H_IMG) v += w11 * src[bse + (size_t)iy1 * strY + (size_t)ix1 * strX];
      }
      samp_f[i][tid] = v;
    }
  }
  __syncthreads();

#pragma unroll 1
  for (int hh = 0; hh < 2; ++hh) {
    int h = grp * 2 + hh;
    f4 acc0 = {0.f, 0.f, 0.f, 0.f};
    f4 acc1 = {0.f, 0.f, 0.f, 0.f};
#pragma unroll 2
    for (int dd4 = 0; dd4 < 8; ++dd4) {
      f4 a0 = *(const f4*)&qp_s[0][h * HD + dd4 * 4];
      f4 a1 = *(const f4*)&qp_s[1][h * HD + dd4 * 4];
#pragma unroll
      for (int j = 0; j < 4; ++j) {
        f4 w4 = *(const f4*)(wk + (size_t)(h * HD + dd4 * 4 + j) * C_DIM + c4 * 4);
        acc0 += a0[j] * w4;
        acc1 += a1[j] * w4;
      }
    }
    *(f4*)&qk_s[h][c4 * 4] = acc0;
    *(f4*)&qk_s[8 + h][c4 * 4] = acc1;
  }
  __syncthreads();

  {
    int pair = tid >> 4;
    int n2 = tid & 15;
    int i = (pair >> 3) * 16 + n2;
    float acc = 0.f;
#pragma unroll 4
    for (int cc4 = 0; cc4 < 64; ++cc4) {
      f4 qk4 = *(const f4*)&qk_s[pair][cc4 * 4];
      f4 s4 = *(const f4*)&samp_f[i][cc4 * 4];
      acc += qk4[0] * s4[0] + qk4[1] * s4[1] + qk4[2] * s4[2] + qk4[3] * s4[3];
    }
    logit_s[tid] = acc * 0.17677669529663687f;
  }
  __syncthreads();

  if (tid < 16) {
    float mx = -1e30f;
#pragma unroll
    for (int n2 = 0; n2 < 16; ++n2) mx = fmaxf(mx, logit_s[tid * 16 + n2]);
    float s = 0.f;
    float e[16];
#pragma unroll
    for (int n2 = 0; n2 < 16; ++n2) {
      e[n2] = __expf(logit_s[tid * 16 + n2] - mx);
      s += e[n2];
    }
    float inv = 1.f / s;
#pragma unroll
    for (int n2 = 0; n2 < 16; ++n2) p_f[tid][n2] = e[n2] * inv;
  }
  __syncthreads();

#pragma unroll 1
  for (int k = 0; k < 4; ++k) {
    int pair = k * 4 + grp;
    int roff = (pair >> 3) * 16;
    f4 acc = {0.f, 0.f, 0.f, 0.f};
#pragma unroll
    for (int n2 = 0; n2 < 16; ++n2)
      acc += p_f[pair][n2] * *(const f4*)&samp_f[roff + n2][c4 * 4];
    *(f4*)&qk_s[pair][c4 * 4] = acc;
  }
  __syncthreads();

  {
    int h = tid >> 5;
    float acc0 = 0.f, acc1 = 0.f;
#pragma unroll 4
    for (int cc4 = 0; cc4 < 64; ++cc4) {
      f4 pv0 = *(const f4*)&qk_s[h][cc4 * 4];
      f4 pv1 = *(const f4*)&qk_s[8 + h][cc4 * 4];
      f4 w4 = *(const f4*)(wv + (size_t)tid * C_DIM + cc4 * 4);
      acc0 += pv0[0] * w4[0] + pv0[1] * w4[1] + pv0[2] * w4[2] + pv0[3] * w4[3];
      acc1 += pv1[0] * w4[0] + pv1[1] * w4[1] + pv1[2] * w4[2] + pv1[3] * w4[3];
    }
    float bvv = bv[tid];
    out[((size_t)b * Q_DIM + q2_0) * C_DIM + tid] = acc0 + bvv;
    out[((size_t)b * Q_DIM + q2_0 + 1) * C_DIM + tid] = acc1 + bvv;
  }
}

// ===========================================================================
extern "C" void kernel_launch(void* const* d_in, const int* in_sizes, int n_in,
                              void* d_out, int out_size, void* d_ws, size_t ws_size,
                              hipStream_t stream) {
  const float* x   = (const float*)d_in[0];
  const float* q   = (const float*)d_in[1];
  const float* ref = (const float*)d_in[2];
  const float* wq  = (const float*)d_in[3];
  const float* bq  = (const float*)d_in[4];
  const float* wk  = (const float*)d_in[5];
  // d_in[6] = bk: cancels in softmax (constant shift per row)
  const float* wv  = (const float*)d_in[7];
  const float* bv  = (const float*)d_in[8];
  float* out = (float*)d_out;

  const size_t XT_B    = (size_t)B_DIM * HW * C_DIM * 2;          // 81.92 MB
  const size_t QK_B    = (size_t)B_DIM * Q_DIM * N_QK * 2;        // 65.5 MB
  const size_t PV_B    = QK_B;                                    // 65.5 MB (qh aliases front)
  const size_t WQKB_B  = (size_t)N_QK * C_DIM * 2;                // 1 MB
  const size_t QKB_B   = (size_t)N_QK * 4;                        // 8 KB
  const size_t WVH_B   = (size_t)C_DIM * C_DIM * 2;               // 128 KB
  const size_t NEED    = XT_B + QK_B + PV_B + WQKB_B + QKB_B + WVH_B;

  if (ws_size >= NEED) {
    char* p = (char*)d_ws;
    _Float16* xt    = (_Float16*)p;           p += XT_B;
    _Float16* qk_g  = (_Float16*)p;           p += QK_B;
    _Float16* pv_g  = (_Float16*)p;           p += PV_B;
    _Float16* qh    = (_Float16*)pv_g;        // alias: qh dead before attn writes pv_g
    _Float16* wqkB  = (_Float16*)p;           p += WQKB_B;
    float*    qkb   = (float*)p;              p += QKB_B;
    _Float16* wvh   = (_Float16*)p;

    xt_kernel<<<dim3((HW + 63) / 64, C_DIM / 64, B_DIM), 256, 0, stream>>>(x, xt);
    qconv_kernel<<<(B_DIM * Q_DIM * C_DIM) / (256 * 8), 256, 0, stream>>>(q, qh);
    prep_wqk<<<N_QK, 256, 0, stream>>>(wq, wk, bq, wqkB, qkb);
    prep_wv<<<C_DIM * C_DIM / 256, 256, 0, stream>>>(wv, wvh);
    qk_gemm<<<dim3(B_DIM * Q_DIM / 128, N_QK / 128), 256, 0, stream>>>(qh, wqkB, qkb, qk_g);
    attn_mfma_kernel<<<dim3(Q_DIM / BQ2, B_DIM), 256, 0, stream>>>(xt, ref, qk_g, pv_g);
    proj_kernel<<<B_DIM * Q_DIM / 16, 256, 0, stream>>>(pv_g, wvh, bv, out);
  } else {
    // fallback: fp32 path
    const size_t QP_BYTES = (size_t)B_DIM * Q_DIM * C_DIM * 4;
    const size_t XTF_BYTES = (size_t)B_DIM * HW * C_DIM * 4;
    float* qp = nullptr;
    float* xtf = nullptr;
    if (ws_size >= QP_BYTES) qp = (float*)d_ws;
    if (ws_size >= QP_BYTES + XTF_BYTES) xtf = (float*)((char*)d_ws + QP_BYTES);

    if (xtf) {
      dim3 g((HW + 31) / 32, C_DIM / 32, B_DIM);
      transpose_kernel<<<g, dim3(32, 8), 0, stream>>>(x, xtf, C_DIM, HW);
    }
    if (qp) qp_kernel<<<B_DIM * Q_DIM / 16, 256, 0, stream>>>(q, wq, bq, qp);

    const float* src;
    int sB, sY, sX, sC;
    if (xtf) { src = xtf; sB = HW * C_DIM; sY = W_IMG * C_DIM; sX = C_DIM; sC = 1; }
    else     { src = x;   sB = C_DIM * HW; sY = W_IMG;         sX = 1;     sC = HW; }

    attn_fb_kernel<<<dim3(Q_DIM / BQ2, B_DIM), 256, 0, stream>>>(
        src, sB, sY, sX, sC, ref, qp, q, wq, bq, wk, wv, bv, out);
  }
}